// Round 1
// baseline (844.554 us; speedup 1.0000x reference)
//
#include <hip/hip_runtime.h>

#define MUL 64
#define XROW 256   // 4*MUL floats per node row
#define WROW 320   // 5*MUL floats per edge weight row

__global__ __launch_bounds__(256) void tpconv_edge_kernel(
    const float* __restrict__ x,
    const float* __restrict__ edge_vec,
    const float* __restrict__ weight,
    const int*  __restrict__ edge_src,
    const int*  __restrict__ edge_dst,
    float* __restrict__ out,
    int E)
{
    const int wave = (int)((blockIdx.x * (blockDim.x >> 6)) + (threadIdx.x >> 6));
    const int lane = threadIdx.x & 63;
    if (wave >= E) return;
    const int e = wave;

    const int src = edge_src[e];
    const int dst = edge_dst[e];

    // normalized edge vector (broadcast loads)
    const float evx = edge_vec[3 * e + 0];
    const float evy = edge_vec[3 * e + 1];
    const float evz = edge_vec[3 * e + 2];
    float n = sqrtf(evx * evx + evy * evy + evz * evz);
    n = fmaxf(n, 1e-12f);
    const float rx = evx / n, ry = evy / n, rz = evz / n;

    // gather x[src] (L2/L3 resident; coalesced across lanes)
    const float* xr = x + (size_t)src * XROW;
    const float xs0 = xr[lane];
    const float x1x = xr[MUL + 3 * lane + 0];
    const float x1y = xr[MUL + 3 * lane + 1];
    const float x1z = xr[MUL + 3 * lane + 2];

    // streamed weights (coalesced)
    const float* w = weight + (size_t)e * WROW;
    const float w000 = w[0 * MUL + lane];
    const float w011 = w[1 * MUL + lane];
    const float w101 = w[2 * MUL + lane];
    const float w110 = w[3 * MUL + lane];
    const float w111 = w[4 * MUL + lane];

    const float PW0       = 0.70710678118654752440f; // sqrt(1/2)
    const float INV_SQRT3 = 0.57735026918962576451f; // 1/sqrt(3)
    const float INV_SQRT2 = 0.70710678118654752440f; // sqrt(3)/sqrt(6)

    // msg0
    const float dotv = x1x * rx + x1y * ry + x1z * rz;
    const float m0 = PW0 * (w000 * xs0 + w110 * dotv);

    // cross(xs1, r)
    const float cx = x1y * rz - x1z * ry;
    const float cy = x1z * rx - x1x * rz;
    const float cz = x1x * ry - x1y * rx;

    // msg1
    const float a = w011 * xs0;
    const float b = w101 * INV_SQRT3;
    const float c = w111 * INV_SQRT2;
    const float m1x = a * rx + b * x1x + c * cx;
    const float m1y = a * ry + b * x1y + c * cy;
    const float m1z = a * rz + b * x1z + c * cz;

    float* o = out + (size_t)dst * XROW;
    atomicAdd(o + lane, m0);
    atomicAdd(o + MUL + 3 * lane + 0, m1x);
    atomicAdd(o + MUL + 3 * lane + 1, m1y);
    atomicAdd(o + MUL + 3 * lane + 2, m1z);
}

extern "C" void kernel_launch(void* const* d_in, const int* in_sizes, int n_in,
                              void* d_out, int out_size, void* d_ws, size_t ws_size,
                              hipStream_t stream) {
    const float* x        = (const float*)d_in[0];
    const float* edge_vec = (const float*)d_in[1];
    const float* weight   = (const float*)d_in[2];
    const int*   edge_src = (const int*)d_in[3];
    const int*   edge_dst = (const int*)d_in[4];
    float* out = (float*)d_out;

    const int E = in_sizes[3];

    // zero the accumulator (harness poisons d_out once, never re-poisons)
    hipMemsetAsync(d_out, 0, (size_t)out_size * sizeof(float), stream);

    const int wavesPerBlock = 4;            // 256 threads
    const int blocks = (E + wavesPerBlock - 1) / wavesPerBlock;
    tpconv_edge_kernel<<<blocks, 256, 0, stream>>>(
        x, edge_vec, weight, edge_src, edge_dst, out, E);
}

// Round 2
// 218.832 us; speedup vs baseline: 3.8594x; 3.8594x over previous
//
#include <hip/hip_runtime.h>

#define MUL 64
#define XROW 256   // 4*MUL floats per node row
#define WROW 320   // 5*MUL floats per edge weight row

// ---------- phase 1: counting sort of edges by dst ----------

__global__ void k_hist(const int* __restrict__ dst, int* __restrict__ counts, int E) {
    int i = blockIdx.x * blockDim.x + threadIdx.x;
    if (i < E) atomicAdd(&counts[dst[i]], 1);
}

// per-block exclusive scan of 256 elements + block totals
__global__ void k_scan1(const int* __restrict__ counts, int* __restrict__ offs,
                        int* __restrict__ bsums, int N) {
    __shared__ int s[256];
    int t = threadIdx.x;
    int i = blockIdx.x * 256 + t;
    int v = (i < N) ? counts[i] : 0;
    s[t] = v; __syncthreads();
    for (int off = 1; off < 256; off <<= 1) {
        int tmp = (t >= off) ? s[t - off] : 0;
        __syncthreads();
        s[t] += tmp;
        __syncthreads();
    }
    if (i < N) offs[i] = s[t] - v;          // exclusive within block
    if (t == 255) bsums[blockIdx.x] = s[255];
}

// scan the (<=256) block sums, in place, exclusive
__global__ void k_scan2(int* __restrict__ bsums, int nb) {
    __shared__ int s[256];
    int t = threadIdx.x;
    int v = (t < nb) ? bsums[t] : 0;
    s[t] = v; __syncthreads();
    for (int off = 1; off < 256; off <<= 1) {
        int tmp = (t >= off) ? s[t - off] : 0;
        __syncthreads();
        s[t] += tmp;
        __syncthreads();
    }
    if (t < nb) bsums[t] = s[t] - v;        // exclusive
}

__global__ void k_scan3(int* __restrict__ offs, const int* __restrict__ bsums, int N) {
    int i = blockIdx.x * 256 + threadIdx.x;
    if (i < N) offs[i] += bsums[blockIdx.x];
}

__global__ void k_scatter(const int* __restrict__ dst, const int* __restrict__ offs,
                          int* __restrict__ cursor, int* __restrict__ sorted, int E) {
    int i = blockIdx.x * blockDim.x + threadIdx.x;
    if (i < E) {
        int d = dst[i];
        int pos = offs[d] + atomicAdd(&cursor[d], 1);
        sorted[pos] = i;
    }
}

// ---------- phase 2: one wave per node, register accumulation, no atomics ----------

__global__ __launch_bounds__(256) void k_accum(
    const float* __restrict__ x,
    const float* __restrict__ edge_vec,
    const float* __restrict__ weight,
    const int*  __restrict__ edge_src,
    const int*  __restrict__ sorted,
    const int*  __restrict__ offs,
    const int*  __restrict__ counts,
    float* __restrict__ out,
    int N)
{
    const int wave = blockIdx.x * (blockDim.x >> 6) + (threadIdx.x >> 6);
    const int lane = threadIdx.x & 63;
    if (wave >= N) return;
    const int node  = wave;
    const int start = offs[node];
    const int cnt   = counts[node];

    const float PW0       = 0.70710678118654752440f; // sqrt(1/2)
    const float INV_SQRT3 = 0.57735026918962576451f; // 1/sqrt(3)
    const float INV_SQRT2 = 0.70710678118654752440f; // sqrt(3)/sqrt(6)

    float a0 = 0.f, a1x = 0.f, a1y = 0.f, a1z = 0.f;

    for (int i = 0; i < cnt; ++i) {
        const int e   = sorted[start + i];     // uniform address -> broadcast
        const int src = edge_src[e];

        const float evx = edge_vec[3 * e + 0];
        const float evy = edge_vec[3 * e + 1];
        const float evz = edge_vec[3 * e + 2];
        const float nn  = fmaxf(sqrtf(evx * evx + evy * evy + evz * evz), 1e-12f);
        const float rn  = 1.0f / nn;
        const float rx = evx * rn, ry = evy * rn, rz = evz * rn;

        const float* xr = x + (size_t)src * XROW;
        const float xs0 = xr[lane];
        const float x1x = xr[MUL + 3 * lane + 0];
        const float x1y = xr[MUL + 3 * lane + 1];
        const float x1z = xr[MUL + 3 * lane + 2];

        const float* w = weight + (size_t)e * WROW;
        const float w000 = w[0 * MUL + lane];
        const float w011 = w[1 * MUL + lane];
        const float w101 = w[2 * MUL + lane];
        const float w110 = w[3 * MUL + lane];
        const float w111 = w[4 * MUL + lane];

        const float dotv = x1x * rx + x1y * ry + x1z * rz;
        a0 += PW0 * (w000 * xs0 + w110 * dotv);

        const float cx = x1y * rz - x1z * ry;
        const float cy = x1z * rx - x1x * rz;
        const float cz = x1x * ry - x1y * rx;

        const float a = w011 * xs0;
        const float b = w101 * INV_SQRT3;
        const float c = w111 * INV_SQRT2;
        a1x += a * rx + b * x1x + c * cx;
        a1y += a * ry + b * x1y + c * cy;
        a1z += a * rz + b * x1z + c * cz;
    }

    float* o = out + (size_t)node * XROW;
    o[lane]                = a0;
    o[MUL + 3 * lane + 0]  = a1x;
    o[MUL + 3 * lane + 1]  = a1y;
    o[MUL + 3 * lane + 2]  = a1z;
}

// ---------- fallback (ws too small): round-1 atomic kernel ----------

__global__ __launch_bounds__(256) void tpconv_edge_kernel(
    const float* __restrict__ x, const float* __restrict__ edge_vec,
    const float* __restrict__ weight, const int* __restrict__ edge_src,
    const int* __restrict__ edge_dst, float* __restrict__ out, int E)
{
    const int wave = blockIdx.x * (blockDim.x >> 6) + (threadIdx.x >> 6);
    const int lane = threadIdx.x & 63;
    if (wave >= E) return;
    const int e = wave;
    const int src = edge_src[e];
    const int dst = edge_dst[e];
    const float evx = edge_vec[3 * e + 0], evy = edge_vec[3 * e + 1], evz = edge_vec[3 * e + 2];
    const float nn = fmaxf(sqrtf(evx * evx + evy * evy + evz * evz), 1e-12f);
    const float rn = 1.0f / nn;
    const float rx = evx * rn, ry = evy * rn, rz = evz * rn;
    const float* xr = x + (size_t)src * XROW;
    const float xs0 = xr[lane];
    const float x1x = xr[MUL + 3 * lane + 0], x1y = xr[MUL + 3 * lane + 1], x1z = xr[MUL + 3 * lane + 2];
    const float* w = weight + (size_t)e * WROW;
    const float w000 = w[lane], w011 = w[MUL + lane], w101 = w[2 * MUL + lane],
                w110 = w[3 * MUL + lane], w111 = w[4 * MUL + lane];
    const float PW0 = 0.70710678118654752440f, INV_SQRT3 = 0.57735026918962576451f,
                INV_SQRT2 = 0.70710678118654752440f;
    const float dotv = x1x * rx + x1y * ry + x1z * rz;
    const float m0 = PW0 * (w000 * xs0 + w110 * dotv);
    const float cx = x1y * rz - x1z * ry, cy = x1z * rx - x1x * rz, cz = x1x * ry - x1y * rx;
    const float a = w011 * xs0, b = w101 * INV_SQRT3, c = w111 * INV_SQRT2;
    float* o = out + (size_t)dst * XROW;
    atomicAdd(o + lane, m0);
    atomicAdd(o + MUL + 3 * lane + 0, a * rx + b * x1x + c * cx);
    atomicAdd(o + MUL + 3 * lane + 1, a * ry + b * x1y + c * cy);
    atomicAdd(o + MUL + 3 * lane + 2, a * rz + b * x1z + c * cz);
}

extern "C" void kernel_launch(void* const* d_in, const int* in_sizes, int n_in,
                              void* d_out, int out_size, void* d_ws, size_t ws_size,
                              hipStream_t stream) {
    const float* x        = (const float*)d_in[0];
    const float* edge_vec = (const float*)d_in[1];
    const float* weight   = (const float*)d_in[2];
    const int*   edge_src = (const int*)d_in[3];
    const int*   edge_dst = (const int*)d_in[4];
    float* out = (float*)d_out;

    const int E = in_sizes[3];
    const int N = in_sizes[0] / XROW;      // 50000

    // workspace layout (ints)
    const int nb1 = (N + 255) / 256;       // scan level-1 blocks (196 for N=50000)
    int* counts = (int*)d_ws;              // [0, N)
    int* offs   = counts + N;              // [N, 2N)
    int* cursor = offs + N;                // [2N, 3N)
    int* bsums  = cursor + N;              // [3N, 3N+256)
    int* sorted = bsums + 256;             // [3N+256, 3N+256+E)
    const size_t need = ((size_t)3 * N + 256 + E) * sizeof(int);

    if (ws_size < need || nb1 > 256) {
        // fallback: atomic edge-parallel version
        hipMemsetAsync(d_out, 0, (size_t)out_size * sizeof(float), stream);
        tpconv_edge_kernel<<<(E + 3) / 4, 256, 0, stream>>>(
            x, edge_vec, weight, edge_src, edge_dst, out, E);
        return;
    }

    hipMemsetAsync(counts, 0, (size_t)N * sizeof(int), stream);
    hipMemsetAsync(cursor, 0, (size_t)N * sizeof(int), stream);

    k_hist<<<(E + 255) / 256, 256, 0, stream>>>(edge_dst, counts, E);
    k_scan1<<<nb1, 256, 0, stream>>>(counts, offs, bsums, N);
    k_scan2<<<1, 256, 0, stream>>>(bsums, nb1);
    k_scan3<<<nb1, 256, 0, stream>>>(offs, bsums, N);
    k_scatter<<<(E + 255) / 256, 256, 0, stream>>>(edge_dst, offs, cursor, sorted, E);

    const int wavesPerBlock = 4;  // 256 threads
    k_accum<<<(N + wavesPerBlock - 1) / wavesPerBlock, 256, 0, stream>>>(
        x, edge_vec, weight, edge_src, sorted, offs, counts, out, N);
}

// Round 3
// 208.055 us; speedup vs baseline: 4.0593x; 1.0518x over previous
//
#include <hip/hip_runtime.h>

#define MUL 64
#define XROW 256   // 4*MUL floats per node row
#define WROW 320   // 5*MUL floats per edge weight row

struct __align__(32) Rec { int e, src; float rx, ry, rz; int p0, p1, p2; };

// ---------- small utility kernels ----------

__global__ void k_zero(int* __restrict__ p, int n) {
    int i = blockIdx.x * blockDim.x + threadIdx.x;
    if (i < n) p[i] = 0;
}

// xt[n*64+u] = {x0[u], x1[u][0], x1[u][1], x1[u][2]}
__global__ void k_xt(const float* __restrict__ x, float4* __restrict__ xt, int N) {
    int t = blockIdx.x * blockDim.x + threadIdx.x;
    if (t >= N * 64) return;
    const int n = t >> 6, u = t & 63;
    const float* xr = x + (size_t)n * XROW;
    float4 v;
    v.x = xr[u];
    v.y = xr[MUL + 3 * u + 0];
    v.z = xr[MUL + 3 * u + 1];
    v.w = xr[MUL + 3 * u + 2];
    xt[t] = v;
}

__global__ void k_hist(const int* __restrict__ dst, int* __restrict__ counts, int E) {
    int i = blockIdx.x * blockDim.x + threadIdx.x;
    if (i < E) atomicAdd(&counts[dst[i]], 1);
}

// per-block exclusive scan of 256 counts + block totals
__global__ void k_scan1(const int* __restrict__ counts, int* __restrict__ offs,
                        int* __restrict__ bsums, int N) {
    __shared__ int s[256];
    int t = threadIdx.x;
    int i = blockIdx.x * 256 + t;
    int v = (i < N) ? counts[i] : 0;
    s[t] = v; __syncthreads();
    for (int off = 1; off < 256; off <<= 1) {
        int tmp = (t >= off) ? s[t - off] : 0;
        __syncthreads();
        s[t] += tmp;
        __syncthreads();
    }
    if (i < N) offs[i] = s[t] - v;
    if (t == 255) bsums[blockIdx.x] = s[255];
}

// exclusive scan of (<=256) block sums, in place
__global__ void k_scan2(int* __restrict__ bsums, int nb) {
    __shared__ int s[256];
    int t = threadIdx.x;
    int v = (t < nb) ? bsums[t] : 0;
    s[t] = v; __syncthreads();
    for (int off = 1; off < 256; off <<= 1) {
        int tmp = (t >= off) ? s[t - off] : 0;
        __syncthreads();
        s[t] += tmp;
        __syncthreads();
    }
    if (t < nb) bsums[t] = s[t] - v;
}

// scatter edge i to its sorted slot; normalize edge_vec once; pack record
__global__ void k_scatter_pack(const int* __restrict__ dst, const int* __restrict__ src,
                               const float* __restrict__ ev,
                               const int* __restrict__ offs, const int* __restrict__ bsums,
                               int* __restrict__ counts, Rec* __restrict__ rec, int E) {
    int i = blockIdx.x * blockDim.x + threadIdx.x;
    if (i >= E) return;
    const int d = dst[i];
    const int pos = offs[d] + bsums[d >> 8] + (atomicSub(&counts[d], 1) - 1);
    const float ex = ev[3 * i + 0], ey = ev[3 * i + 1], ez = ev[3 * i + 2];
    const float rn = 1.0f / fmaxf(sqrtf(ex * ex + ey * ey + ez * ez), 1e-12f);
    Rec r;
    r.e = i; r.src = src[i];
    r.rx = ex * rn; r.ry = ey * rn; r.rz = ez * rn;
    r.p0 = 0; r.p1 = 0; r.p2 = 0;
    rec[pos] = r;
}

// ---------- main accumulation: one wave per node, register acc, pipelined ----------

__global__ __launch_bounds__(256) void k_accum(
    const float* __restrict__ weight,
    const float4* __restrict__ xt,
    const Rec* __restrict__ rec,
    const int* __restrict__ offs,
    const int* __restrict__ bsums,
    float* __restrict__ out,
    int N, int E)
{
    const int wave = blockIdx.x * (blockDim.x >> 6) + (threadIdx.x >> 6);
    const int lane = threadIdx.x & 63;
    if (wave >= N) return;
    const int n = wave;
    const int start = offs[n] + bsums[n >> 8];
    const int end   = (n + 1 < N) ? (offs[n + 1] + bsums[(n + 1) >> 8]) : E;

    const float PW0       = 0.70710678118654752440f; // sqrt(1/2)
    const float INV_SQRT3 = 0.57735026918962576451f; // 1/sqrt(3)
    const float INV_SQRT2 = 0.70710678118654752440f; // sqrt(3)/sqrt(6)

    float a0 = 0.f, a1x = 0.f, a1y = 0.f, a1z = 0.f;

    if (start < end) {
        const int4*  ri = (const int4*)rec;
        const float* rf = (const float*)rec;
        // stage 0 of pipeline
        int4  h0  = ri[2 * start];            // e, src, bits(rx), bits(ry)
        float rz0 = rf[8 * start + 4];
        for (int i = start; i < end; ++i) {
            int4 h1; float rz1;
            if (i + 1 < end) {                // wave-uniform branch
                h1  = ri[2 * (i + 1)];
                rz1 = rf[8 * (i + 1) + 4];
            } else { h1 = h0; rz1 = rz0; }

            const int   e  = h0.x, s = h0.y;
            const float rx = __int_as_float(h0.z);
            const float ry = __int_as_float(h0.w);
            const float rz = rz0;

            const float* w = weight + (size_t)e * WROW;
            const float w000 = __builtin_nontemporal_load(w + 0 * MUL + lane);
            const float w011 = __builtin_nontemporal_load(w + 1 * MUL + lane);
            const float w101 = __builtin_nontemporal_load(w + 2 * MUL + lane);
            const float w110 = __builtin_nontemporal_load(w + 3 * MUL + lane);
            const float w111 = __builtin_nontemporal_load(w + 4 * MUL + lane);

            const float4 xv = xt[(size_t)s * 64 + lane];

            const float dotv = xv.y * rx + xv.z * ry + xv.w * rz;
            a0 += PW0 * (w000 * xv.x + w110 * dotv);

            const float cx = xv.z * rz - xv.w * ry;
            const float cy = xv.w * rx - xv.y * rz;
            const float cz = xv.y * ry - xv.z * rx;

            const float a = w011 * xv.x;
            const float b = w101 * INV_SQRT3;
            const float c = w111 * INV_SQRT2;
            a1x += a * rx + b * xv.y + c * cx;
            a1y += a * ry + b * xv.z + c * cy;
            a1z += a * rz + b * xv.w + c * cz;

            h0 = h1; rz0 = rz1;
        }
    }

    float* o = out + (size_t)n * XROW;
    o[lane]               = a0;
    o[MUL + 3 * lane + 0] = a1x;
    o[MUL + 3 * lane + 1] = a1y;
    o[MUL + 3 * lane + 2] = a1z;
}

// ---------- fallback (ws too small): atomic edge-parallel version ----------

__global__ __launch_bounds__(256) void tpconv_edge_kernel(
    const float* __restrict__ x, const float* __restrict__ edge_vec,
    const float* __restrict__ weight, const int* __restrict__ edge_src,
    const int* __restrict__ edge_dst, float* __restrict__ out, int E)
{
    const int wave = blockIdx.x * (blockDim.x >> 6) + (threadIdx.x >> 6);
    const int lane = threadIdx.x & 63;
    if (wave >= E) return;
    const int e = wave;
    const int src = edge_src[e];
    const int dst = edge_dst[e];
    const float evx = edge_vec[3 * e + 0], evy = edge_vec[3 * e + 1], evz = edge_vec[3 * e + 2];
    const float rn = 1.0f / fmaxf(sqrtf(evx * evx + evy * evy + evz * evz), 1e-12f);
    const float rx = evx * rn, ry = evy * rn, rz = evz * rn;
    const float* xr = x + (size_t)src * XROW;
    const float xs0 = xr[lane];
    const float x1x = xr[MUL + 3 * lane + 0], x1y = xr[MUL + 3 * lane + 1], x1z = xr[MUL + 3 * lane + 2];
    const float* w = weight + (size_t)e * WROW;
    const float w000 = w[lane], w011 = w[MUL + lane], w101 = w[2 * MUL + lane],
                w110 = w[3 * MUL + lane], w111 = w[4 * MUL + lane];
    const float PW0 = 0.70710678118654752440f, INV_SQRT3 = 0.57735026918962576451f,
                INV_SQRT2 = 0.70710678118654752440f;
    const float dotv = x1x * rx + x1y * ry + x1z * rz;
    const float m0 = PW0 * (w000 * xs0 + w110 * dotv);
    const float cx = x1y * rz - x1z * ry, cy = x1z * rx - x1x * rz, cz = x1x * ry - x1y * rx;
    const float a = w011 * xs0, b = w101 * INV_SQRT3, c = w111 * INV_SQRT2;
    float* o = out + (size_t)dst * XROW;
    atomicAdd(o + lane, m0);
    atomicAdd(o + MUL + 3 * lane + 0, a * rx + b * x1x + c * cx);
    atomicAdd(o + MUL + 3 * lane + 1, a * ry + b * x1y + c * cy);
    atomicAdd(o + MUL + 3 * lane + 2, a * rz + b * x1z + c * cz);
}

extern "C" void kernel_launch(void* const* d_in, const int* in_sizes, int n_in,
                              void* d_out, int out_size, void* d_ws, size_t ws_size,
                              hipStream_t stream) {
    const float* x        = (const float*)d_in[0];
    const float* edge_vec = (const float*)d_in[1];
    const float* weight   = (const float*)d_in[2];
    const int*   edge_src = (const int*)d_in[3];
    const int*   edge_dst = (const int*)d_in[4];
    float* out = (float*)d_out;

    const int E = in_sizes[3];
    const int N = in_sizes[0] / XROW;      // 50000
    const int nb1 = (N + 255) / 256;       // 196 for N=50000

    // workspace layout
    int*  counts = (int*)d_ws;                       // N ints (also cursor via atomicSub)
    int*  offs   = counts + N;                       // N ints
    int*  bsums  = offs + N;                         // 256 ints
    Rec*  recb   = (Rec*)(bsums + 256);              // E * 32 B
    float4* xtb  = (float4*)((char*)recb + (size_t)E * sizeof(Rec)); // N*64 float4
    const size_t need = (size_t)(2 * N + 256) * 4 + (size_t)E * sizeof(Rec)
                      + (size_t)N * 64 * sizeof(float4);

    if (ws_size < need || nb1 > 256) {
        hipMemsetAsync(d_out, 0, (size_t)out_size * sizeof(float), stream);
        tpconv_edge_kernel<<<(E + 3) / 4, 256, 0, stream>>>(
            x, edge_vec, weight, edge_src, edge_dst, out, E);
        return;
    }

    k_zero<<<(N + 255) / 256, 256, 0, stream>>>(counts, N);
    k_xt<<<(N * 64 + 255) / 256, 256, 0, stream>>>(x, xtb, N);
    k_hist<<<(E + 255) / 256, 256, 0, stream>>>(edge_dst, counts, E);
    k_scan1<<<nb1, 256, 0, stream>>>(counts, offs, bsums, N);
    k_scan2<<<1, 256, 0, stream>>>(bsums, nb1);
    k_scatter_pack<<<(E + 255) / 256, 256, 0, stream>>>(
        edge_dst, edge_src, edge_vec, offs, bsums, counts, recb, E);
    k_accum<<<(N + 3) / 4, 256, 0, stream>>>(
        weight, xtb, recb, offs, bsums, out, N, E);
}

// Round 5
// 207.536 us; speedup vs baseline: 4.0694x; 1.0025x over previous
//
#include <hip/hip_runtime.h>

#define MUL 64
#define XROW 256   // 4*MUL floats per node row
#define WROW 320   // 5*MUL floats per edge weight row

typedef int   i32x4 __attribute__((ext_vector_type(4)));
typedef float f32x4 __attribute__((ext_vector_type(4)));

struct __align__(32) Rec { int e, src; float rx, ry, rz; int p0, p1, p2; };

// ---------- phase 0: fused {zero counts} + {transpose x -> xt} ----------

__global__ void k_xt_zero(const float* __restrict__ x, f32x4* __restrict__ xt,
                          int* __restrict__ counts, int N) {
    int t = blockIdx.x * blockDim.x + threadIdx.x;
    if (t < N) counts[t] = 0;
    if (t >= N * 64) return;
    const int n = t >> 6, u = t & 63;
    const float* xr = x + (size_t)n * XROW;
    f32x4 v;
    v.x = xr[u];
    v.y = xr[MUL + 3 * u + 0];
    v.z = xr[MUL + 3 * u + 1];
    v.w = xr[MUL + 3 * u + 2];
    xt[t] = v;
}

__global__ void k_hist(const int* __restrict__ dst, int* __restrict__ counts, int E) {
    int i = blockIdx.x * blockDim.x + threadIdx.x;
    if (i < E) atomicAdd(&counts[dst[i]], 1);
}

// per-block exclusive scan of 256 counts + block totals
__global__ void k_scan1(const int* __restrict__ counts, int* __restrict__ offs,
                        int* __restrict__ bsums, int N) {
    __shared__ int s[256];
    int t = threadIdx.x;
    int i = blockIdx.x * 256 + t;
    int v = (i < N) ? counts[i] : 0;
    s[t] = v; __syncthreads();
    for (int off = 1; off < 256; off <<= 1) {
        int tmp = (t >= off) ? s[t - off] : 0;
        __syncthreads();
        s[t] += tmp;
        __syncthreads();
    }
    if (i < N) offs[i] = s[t] - v;
    if (t == 255) bsums[blockIdx.x] = s[255];
}

// exclusive scan of (<=256) block sums, in place
__global__ void k_scan2(int* __restrict__ bsums, int nb) {
    __shared__ int s[256];
    int t = threadIdx.x;
    int v = (t < nb) ? bsums[t] : 0;
    s[t] = v; __syncthreads();
    for (int off = 1; off < 256; off <<= 1) {
        int tmp = (t >= off) ? s[t - off] : 0;
        __syncthreads();
        s[t] += tmp;
        __syncthreads();
    }
    if (t < nb) bsums[t] = s[t] - v;
}

// scatter edge i to its sorted slot; normalize edge_vec once; pack record
__global__ void k_scatter_pack(const int* __restrict__ dst, const int* __restrict__ src,
                               const float* __restrict__ ev,
                               const int* __restrict__ offs, const int* __restrict__ bsums,
                               int* __restrict__ counts, Rec* __restrict__ rec, int E) {
    int i = blockIdx.x * blockDim.x + threadIdx.x;
    if (i >= E) return;
    const int d = dst[i];
    const int pos = offs[d] + bsums[d >> 8] + (atomicSub(&counts[d], 1) - 1);
    const float ex = ev[3 * i + 0], ey = ev[3 * i + 1], ez = ev[3 * i + 2];
    const float rn = 1.0f / fmaxf(sqrtf(ex * ex + ey * ey + ez * ez), 1e-12f);
    Rec r;
    r.e = i; r.src = src[i];
    r.rx = ex * rn; r.ry = ey * rn; r.rz = ez * rn;
    r.p0 = 0; r.p1 = 0; r.p2 = 0;
    rec[pos] = r;
}

// ---------- main accumulation: one wave per node, 3-stage pipeline ----------

__global__ __launch_bounds__(256) void k_accum(
    const float* __restrict__ weight,
    const f32x4* __restrict__ xt,
    const Rec* __restrict__ rec,
    const int* __restrict__ offs,
    const int* __restrict__ bsums,
    float* __restrict__ out,
    int N, int E)
{
    const int wave = blockIdx.x * (blockDim.x >> 6) + (threadIdx.x >> 6);
    const int lane = threadIdx.x & 63;
    if (wave >= N) return;
    const int n = wave;
    const int start = offs[n] + bsums[n >> 8];
    const int end   = (n + 1 < N) ? (offs[n + 1] + bsums[(n + 1) >> 8]) : E;

    const float PW0       = 0.70710678118654752440f; // sqrt(1/2)
    const float INV_SQRT3 = 0.57735026918962576451f; // 1/sqrt(3)
    const float INV_SQRT2 = 0.70710678118654752440f; // sqrt(3)/sqrt(6)

    float a0 = 0.f, a1x = 0.f, a1y = 0.f, a1z = 0.f;

    if (start < end) {
        const i32x4* ri = (const i32x4*)rec;
        const float* rf = (const float*)rec;
        const int last = end - 1;

        // ---- pipeline prologue ----
        // stage A: rec for i and i+1
        i32x4 h0  = __builtin_nontemporal_load(ri + 2 * start);
        float rz0 = __builtin_nontemporal_load(rf + 8 * start + 4);
        const int j1 = (start + 1 < last) ? start + 1 : last;
        i32x4 h1  = __builtin_nontemporal_load(ri + 2 * j1);
        float rz1 = __builtin_nontemporal_load(rf + 8 * j1 + 4);
        // stage B: w/xt for i
        const float* w0p = weight + (size_t)h0.x * WROW;
        float w000 = __builtin_nontemporal_load(w0p + 0 * MUL + lane);
        float w011 = __builtin_nontemporal_load(w0p + 1 * MUL + lane);
        float w101 = __builtin_nontemporal_load(w0p + 2 * MUL + lane);
        float w110 = __builtin_nontemporal_load(w0p + 3 * MUL + lane);
        float w111 = __builtin_nontemporal_load(w0p + 4 * MUL + lane);
        f32x4 xv = xt[(size_t)h0.y * 64 + lane];

        for (int i = start; i < end; ++i) {
            // prefetch rec[i+2]
            const int j2 = (i + 2 < last) ? i + 2 : last;
            const i32x4 h2  = __builtin_nontemporal_load(ri + 2 * j2);
            const float rz2 = __builtin_nontemporal_load(rf + 8 * j2 + 4);

            // prefetch w/xt for i+1 (rec h1 loaded one iteration ago)
            const float* w1p = weight + (size_t)h1.x * WROW;
            const float nw000 = __builtin_nontemporal_load(w1p + 0 * MUL + lane);
            const float nw011 = __builtin_nontemporal_load(w1p + 1 * MUL + lane);
            const float nw101 = __builtin_nontemporal_load(w1p + 2 * MUL + lane);
            const float nw110 = __builtin_nontemporal_load(w1p + 3 * MUL + lane);
            const float nw111 = __builtin_nontemporal_load(w1p + 4 * MUL + lane);
            const f32x4 nxv = xt[(size_t)h1.y * 64 + lane];

            // compute iteration i (data loaded >= one iteration ago)
            const float rx = __int_as_float(h0.z);
            const float ry = __int_as_float(h0.w);
            const float rz = rz0;

            const float dotv = xv.y * rx + xv.z * ry + xv.w * rz;
            a0 += PW0 * (w000 * xv.x + w110 * dotv);

            const float cx = xv.z * rz - xv.w * ry;
            const float cy = xv.w * rx - xv.y * rz;
            const float cz = xv.y * ry - xv.z * rx;

            const float a = w011 * xv.x;
            const float b = w101 * INV_SQRT3;
            const float c = w111 * INV_SQRT2;
            a1x += a * rx + b * xv.y + c * cx;
            a1y += a * ry + b * xv.z + c * cy;
            a1z += a * rz + b * xv.w + c * cz;

            // rotate
            h0 = h1; rz0 = rz1;
            h1 = h2; rz1 = rz2;
            w000 = nw000; w011 = nw011; w101 = nw101; w110 = nw110; w111 = nw111;
            xv = nxv;
        }
    }

    float* o = out + (size_t)n * XROW;
    __builtin_nontemporal_store(a0,  o + lane);
    __builtin_nontemporal_store(a1x, o + MUL + 3 * lane + 0);
    __builtin_nontemporal_store(a1y, o + MUL + 3 * lane + 1);
    __builtin_nontemporal_store(a1z, o + MUL + 3 * lane + 2);
}

// ---------- fallback (ws too small): atomic edge-parallel version ----------

__global__ __launch_bounds__(256) void tpconv_edge_kernel(
    const float* __restrict__ x, const float* __restrict__ edge_vec,
    const float* __restrict__ weight, const int* __restrict__ edge_src,
    const int* __restrict__ edge_dst, float* __restrict__ out, int E)
{
    const int wave = blockIdx.x * (blockDim.x >> 6) + (threadIdx.x >> 6);
    const int lane = threadIdx.x & 63;
    if (wave >= E) return;
    const int e = wave;
    const int src = edge_src[e];
    const int dst = edge_dst[e];
    const float evx = edge_vec[3 * e + 0], evy = edge_vec[3 * e + 1], evz = edge_vec[3 * e + 2];
    const float rn = 1.0f / fmaxf(sqrtf(evx * evx + evy * evy + evz * evz), 1e-12f);
    const float rx = evx * rn, ry = evy * rn, rz = evz * rn;
    const float* xr = x + (size_t)src * XROW;
    const float xs0 = xr[lane];
    const float x1x = xr[MUL + 3 * lane + 0], x1y = xr[MUL + 3 * lane + 1], x1z = xr[MUL + 3 * lane + 2];
    const float* w = weight + (size_t)e * WROW;
    const float w000 = w[lane], w011 = w[MUL + lane], w101 = w[2 * MUL + lane],
                w110 = w[3 * MUL + lane], w111 = w[4 * MUL + lane];
    const float PW0 = 0.70710678118654752440f, INV_SQRT3 = 0.57735026918962576451f,
                INV_SQRT2 = 0.70710678118654752440f;
    const float dotv = x1x * rx + x1y * ry + x1z * rz;
    const float m0 = PW0 * (w000 * xs0 + w110 * dotv);
    const float cx = x1y * rz - x1z * ry, cy = x1z * rx - x1x * rz, cz = x1x * ry - x1y * rx;
    const float a = w011 * xs0, b = w101 * INV_SQRT3, c = w111 * INV_SQRT2;
    float* o = out + (size_t)dst * XROW;
    atomicAdd(o + lane, m0);
    atomicAdd(o + MUL + 3 * lane + 0, a * rx + b * x1x + c * cx);
    atomicAdd(o + MUL + 3 * lane + 1, a * ry + b * x1y + c * cy);
    atomicAdd(o + MUL + 3 * lane + 2, a * rz + b * x1z + c * cz);
}

extern "C" void kernel_launch(void* const* d_in, const int* in_sizes, int n_in,
                              void* d_out, int out_size, void* d_ws, size_t ws_size,
                              hipStream_t stream) {
    const float* x        = (const float*)d_in[0];
    const float* edge_vec = (const float*)d_in[1];
    const float* weight   = (const float*)d_in[2];
    const int*   edge_src = (const int*)d_in[3];
    const int*   edge_dst = (const int*)d_in[4];
    float* out = (float*)d_out;

    const int E = in_sizes[3];
    const int N = in_sizes[0] / XROW;      // 50000
    const int nb1 = (N + 255) / 256;       // 196 for N=50000

    // workspace layout
    int*  counts = (int*)d_ws;                       // N ints (also cursor via atomicSub)
    int*  offs   = counts + N;                       // N ints
    int*  bsums  = offs + N;                         // 256 ints
    Rec*  recb   = (Rec*)(bsums + 256);              // E * 32 B
    f32x4* xtb   = (f32x4*)((char*)recb + (size_t)E * sizeof(Rec)); // N*64 f32x4
    const size_t need = (size_t)(2 * N + 256) * 4 + (size_t)E * sizeof(Rec)
                      + (size_t)N * 64 * sizeof(f32x4);

    if (ws_size < need || nb1 > 256) {
        (void)hipMemsetAsync(d_out, 0, (size_t)out_size * sizeof(float), stream);
        tpconv_edge_kernel<<<(E + 3) / 4, 256, 0, stream>>>(
            x, edge_vec, weight, edge_src, edge_dst, out, E);
        return;
    }

    k_xt_zero<<<(N * 64 + 255) / 256, 256, 0, stream>>>(x, xtb, counts, N);
    k_hist<<<(E + 255) / 256, 256, 0, stream>>>(edge_dst, counts, E);
    k_scan1<<<nb1, 256, 0, stream>>>(counts, offs, bsums, N);
    k_scan2<<<1, 256, 0, stream>>>(bsums, nb1);
    k_scatter_pack<<<(E + 255) / 256, 256, 0, stream>>>(
        edge_dst, edge_src, edge_vec, offs, bsums, counts, recb, E);
    k_accum<<<(N + 3) / 4, 256, 0, stream>>>(
        weight, xtb, recb, offs, bsums, out, N, E);
}

// Round 6
// 181.716 us; speedup vs baseline: 4.6477x; 1.1421x over previous
//
#include <hip/hip_runtime.h>

#define MUL 64
#define XROW 256   // 4*MUL floats per node row
#define WROW 320   // 5*MUL floats per edge weight row
#define CAP  96    // fixed bucket capacity per node (avg degree 8, Poisson tail << 96)

typedef int   i32x4 __attribute__((ext_vector_type(4)));
typedef float f32x4 __attribute__((ext_vector_type(4)));

struct __align__(32) Rec { int e, src; float rx, ry, rz; int p0, p1, p2; };

// ---------- phase 0: fused {zero counts+ovfcnt} + {transpose x -> xt} ----------

__global__ void k_xt_zero(const float* __restrict__ x, f32x4* __restrict__ xt,
                          int* __restrict__ counts, int* __restrict__ ovfcnt, int N) {
    int t = blockIdx.x * blockDim.x + threadIdx.x;
    if (t < N) counts[t] = 0;
    if (t == 0) *ovfcnt = 0;
    if (t >= N * 64) return;
    const int n = t >> 6, u = t & 63;
    const float* xr = x + (size_t)n * XROW;
    f32x4 v;
    v.x = xr[u];
    v.y = xr[MUL + 3 * u + 0];
    v.z = xr[MUL + 3 * u + 1];
    v.w = xr[MUL + 3 * u + 2];
    xt[t] = v;
}

// ---------- phase 1: direct bucket placement (no hist, no scan) ----------

__global__ void k_scatter_pack(const int* __restrict__ dst, const int* __restrict__ src,
                               const float* __restrict__ ev,
                               int* __restrict__ counts, Rec* __restrict__ rec,
                               int* __restrict__ ovf, int* __restrict__ ovfcnt, int E) {
    int i = blockIdx.x * blockDim.x + threadIdx.x;
    if (i >= E) return;
    const int d = dst[i];
    const int slot = atomicAdd(&counts[d], 1);
    if (slot >= CAP) {                       // structurally ~impossible; correctness net
        int oi = atomicAdd(ovfcnt, 1);
        ovf[oi] = i;
        return;
    }
    const float ex = ev[3 * i + 0], ey = ev[3 * i + 1], ez = ev[3 * i + 2];
    const float rn = 1.0f / fmaxf(sqrtf(ex * ex + ey * ey + ez * ez), 1e-12f);
    Rec r;
    r.e = i; r.src = src[i];
    r.rx = ex * rn; r.ry = ey * rn; r.rz = ez * rn;
    r.p0 = 0; r.p1 = 0; r.p2 = 0;
    rec[(size_t)d * CAP + slot] = r;
}

// ---------- phase 2: one wave per node, 3-stage pipeline, 2-deep w prefetch ----------

__global__ __launch_bounds__(256) void k_accum(
    const float* __restrict__ weight,
    const f32x4* __restrict__ xt,
    const Rec* __restrict__ rec,
    const int* __restrict__ counts,
    float* __restrict__ out,
    int N)
{
    const int wave = blockIdx.x * (blockDim.x >> 6) + (threadIdx.x >> 6);
    const int lane = threadIdx.x & 63;
    if (wave >= N) return;
    const int n   = wave;
    const int cnt = min(counts[n], CAP);

    const float PW0       = 0.70710678118654752440f; // sqrt(1/2)
    const float INV_SQRT3 = 0.57735026918962576451f; // 1/sqrt(3)
    const float INV_SQRT2 = 0.70710678118654752440f; // sqrt(3)/sqrt(6)

    float a0 = 0.f, a1x = 0.f, a1y = 0.f, a1z = 0.f;

    if (cnt > 0) {
        const size_t base = (size_t)n * CAP;
        const i32x4* ri = (const i32x4*)rec;
        const float* rf = (const float*)rec;
        const int last = cnt - 1;

        // ---- prologue: rec for 0,1,2 ; w/xt for 0,1 ----
        i32x4 h0  = ri[2 * (base + 0)];
        float rz0 = rf[8 * (base + 0) + 4];
        const int j1 = (1 < last) ? 1 : last;
        i32x4 h1  = ri[2 * (base + j1)];
        float rz1 = rf[8 * (base + j1) + 4];
        const int j2p = (2 < last) ? 2 : last;
        i32x4 h2  = ri[2 * (base + j2p)];
        float rz2 = rf[8 * (base + j2p) + 4];

        const float* w0p = weight + (size_t)h0.x * WROW;
        float w000 = __builtin_nontemporal_load(w0p + 0 * MUL + lane);
        float w011 = __builtin_nontemporal_load(w0p + 1 * MUL + lane);
        float w101 = __builtin_nontemporal_load(w0p + 2 * MUL + lane);
        float w110 = __builtin_nontemporal_load(w0p + 3 * MUL + lane);
        float w111 = __builtin_nontemporal_load(w0p + 4 * MUL + lane);
        f32x4 xv = xt[(size_t)h0.y * 64 + lane];

        const float* w1p = weight + (size_t)h1.x * WROW;
        float v000 = __builtin_nontemporal_load(w1p + 0 * MUL + lane);
        float v011 = __builtin_nontemporal_load(w1p + 1 * MUL + lane);
        float v101 = __builtin_nontemporal_load(w1p + 2 * MUL + lane);
        float v110 = __builtin_nontemporal_load(w1p + 3 * MUL + lane);
        float v111 = __builtin_nontemporal_load(w1p + 4 * MUL + lane);
        f32x4 yv = xt[(size_t)h1.y * 64 + lane];

        for (int i = 0; i < cnt; ++i) {
            // prefetch rec[i+3]
            const int j3 = (i + 3 < last) ? i + 3 : last;
            const i32x4 h3  = ri[2 * (base + j3)];
            const float rz3 = rf[8 * (base + j3) + 4];

            // prefetch w/xt for i+2 (rec h2 loaded one iteration ago)
            const float* w2p = weight + (size_t)h2.x * WROW;
            const float u000 = __builtin_nontemporal_load(w2p + 0 * MUL + lane);
            const float u011 = __builtin_nontemporal_load(w2p + 1 * MUL + lane);
            const float u101 = __builtin_nontemporal_load(w2p + 2 * MUL + lane);
            const float u110 = __builtin_nontemporal_load(w2p + 3 * MUL + lane);
            const float u111 = __builtin_nontemporal_load(w2p + 4 * MUL + lane);
            const f32x4 zv = xt[(size_t)h2.y * 64 + lane];

            // compute iteration i (data loaded two iterations ago)
            const float rx = __int_as_float(h0.z);
            const float ry = __int_as_float(h0.w);
            const float rz = rz0;

            const float dotv = xv.y * rx + xv.z * ry + xv.w * rz;
            a0 += PW0 * (w000 * xv.x + w110 * dotv);

            const float cx = xv.z * rz - xv.w * ry;
            const float cy = xv.w * rx - xv.y * rz;
            const float cz = xv.y * ry - xv.z * rx;

            const float a = w011 * xv.x;
            const float b = w101 * INV_SQRT3;
            const float c = w111 * INV_SQRT2;
            a1x += a * rx + b * xv.y + c * cx;
            a1y += a * ry + b * xv.z + c * cy;
            a1z += a * rz + b * xv.w + c * cz;

            // rotate
            h0 = h1; rz0 = rz1;
            h1 = h2; rz1 = rz2;
            h2 = h3; rz2 = rz3;
            w000 = v000; w011 = v011; w101 = v101; w110 = v110; w111 = v111;
            xv = yv;
            v000 = u000; v011 = u011; v101 = u101; v110 = u110; v111 = u111;
            yv = zv;
        }
    }

    float* o = out + (size_t)n * XROW;
    __builtin_nontemporal_store(a0,  o + lane);
    __builtin_nontemporal_store(a1x, o + MUL + 3 * lane + 0);
    __builtin_nontemporal_store(a1y, o + MUL + 3 * lane + 1);
    __builtin_nontemporal_store(a1z, o + MUL + 3 * lane + 2);
}

// ---------- phase 3: drain overflow list (normally empty) ----------

__global__ void k_overflow(const float* __restrict__ weight, const f32x4* __restrict__ xt,
                           const float* __restrict__ ev, const int* __restrict__ src,
                           const int* __restrict__ dst,
                           const int* __restrict__ ovf, const int* __restrict__ ovfcnt,
                           float* __restrict__ out) {
    const int nov = *ovfcnt;
    const int wid  = blockIdx.x * (blockDim.x >> 6) + (threadIdx.x >> 6);
    const int lane = threadIdx.x & 63;
    const int nw   = gridDim.x * (blockDim.x >> 6);
    const float PW0 = 0.70710678118654752440f, INV_SQRT3 = 0.57735026918962576451f,
                INV_SQRT2 = 0.70710678118654752440f;
    for (int k = wid; k < nov; k += nw) {
        const int e = ovf[k];
        const int s = src[e], d = dst[e];
        const float ex = ev[3 * e + 0], ey = ev[3 * e + 1], ez = ev[3 * e + 2];
        const float rn = 1.0f / fmaxf(sqrtf(ex * ex + ey * ey + ez * ez), 1e-12f);
        const float rx = ex * rn, ry = ey * rn, rz = ez * rn;
        const f32x4 xv = xt[(size_t)s * 64 + lane];
        const float* w = weight + (size_t)e * WROW;
        const float w000 = w[lane], w011 = w[MUL + lane], w101 = w[2 * MUL + lane],
                    w110 = w[3 * MUL + lane], w111 = w[4 * MUL + lane];
        const float dotv = xv.y * rx + xv.z * ry + xv.w * rz;
        const float m0 = PW0 * (w000 * xv.x + w110 * dotv);
        const float cx = xv.z * rz - xv.w * ry;
        const float cy = xv.w * rx - xv.y * rz;
        const float cz = xv.y * ry - xv.z * rx;
        const float a = w011 * xv.x, b = w101 * INV_SQRT3, c = w111 * INV_SQRT2;
        float* o = out + (size_t)d * XROW;
        atomicAdd(o + lane, m0);
        atomicAdd(o + MUL + 3 * lane + 0, a * rx + b * xv.y + c * cx);
        atomicAdd(o + MUL + 3 * lane + 1, a * ry + b * xv.z + c * cy);
        atomicAdd(o + MUL + 3 * lane + 2, a * rz + b * xv.w + c * cz);
    }
}

// ---------- fallback (ws too small): atomic edge-parallel version ----------

__global__ __launch_bounds__(256) void tpconv_edge_kernel(
    const float* __restrict__ x, const float* __restrict__ edge_vec,
    const float* __restrict__ weight, const int* __restrict__ edge_src,
    const int* __restrict__ edge_dst, float* __restrict__ out, int E)
{
    const int wave = blockIdx.x * (blockDim.x >> 6) + (threadIdx.x >> 6);
    const int lane = threadIdx.x & 63;
    if (wave >= E) return;
    const int e = wave;
    const int src = edge_src[e];
    const int dst = edge_dst[e];
    const float evx = edge_vec[3 * e + 0], evy = edge_vec[3 * e + 1], evz = edge_vec[3 * e + 2];
    const float rn = 1.0f / fmaxf(sqrtf(evx * evx + evy * evy + evz * evz), 1e-12f);
    const float rx = evx * rn, ry = evy * rn, rz = evz * rn;
    const float* xr = x + (size_t)src * XROW;
    const float xs0 = xr[lane];
    const float x1x = xr[MUL + 3 * lane + 0], x1y = xr[MUL + 3 * lane + 1], x1z = xr[MUL + 3 * lane + 2];
    const float* w = weight + (size_t)e * WROW;
    const float w000 = w[lane], w011 = w[MUL + lane], w101 = w[2 * MUL + lane],
                w110 = w[3 * MUL + lane], w111 = w[4 * MUL + lane];
    const float PW0 = 0.70710678118654752440f, INV_SQRT3 = 0.57735026918962576451f,
                INV_SQRT2 = 0.70710678118654752440f;
    const float dotv = x1x * rx + x1y * ry + x1z * rz;
    const float m0 = PW0 * (w000 * xs0 + w110 * dotv);
    const float cx = x1y * rz - x1z * ry, cy = x1z * rx - x1x * rz, cz = x1x * ry - x1y * rx;
    const float a = w011 * xs0, b = w101 * INV_SQRT3, c = w111 * INV_SQRT2;
    float* o = out + (size_t)dst * XROW;
    atomicAdd(o + lane, m0);
    atomicAdd(o + MUL + 3 * lane + 0, a * rx + b * x1x + c * cx);
    atomicAdd(o + MUL + 3 * lane + 1, a * ry + b * x1y + c * cy);
    atomicAdd(o + MUL + 3 * lane + 2, a * rz + b * x1z + c * cz);
}

extern "C" void kernel_launch(void* const* d_in, const int* in_sizes, int n_in,
                              void* d_out, int out_size, void* d_ws, size_t ws_size,
                              hipStream_t stream) {
    const float* x        = (const float*)d_in[0];
    const float* edge_vec = (const float*)d_in[1];
    const float* weight   = (const float*)d_in[2];
    const int*   edge_src = (const int*)d_in[3];
    const int*   edge_dst = (const int*)d_in[4];
    float* out = (float*)d_out;

    const int E = in_sizes[3];
    const int N = in_sizes[0] / XROW;      // 50000

    // workspace layout
    int*  counts = (int*)d_ws;                                   // N ints
    int*  ovfcnt = counts + N;                                   // 1 int (pad 8)
    int*  ovf    = ovfcnt + 8;                                   // E ints
    char* p      = (char*)(ovf + E);
    p += (64 - ((size_t)p & 63)) & 63;                           // align 64
    Rec*   recb  = (Rec*)p;                                      // N*CAP*32 B
    f32x4* xtb   = (f32x4*)((char*)recb + (size_t)N * CAP * sizeof(Rec)); // N*64*16 B
    const size_t need = ((char*)xtb + (size_t)N * 64 * sizeof(f32x4)) - (char*)d_ws;

    if (ws_size < need) {
        (void)hipMemsetAsync(d_out, 0, (size_t)out_size * sizeof(float), stream);
        tpconv_edge_kernel<<<(E + 3) / 4, 256, 0, stream>>>(
            x, edge_vec, weight, edge_src, edge_dst, out, E);
        return;
    }

    k_xt_zero<<<(N * 64 + 255) / 256, 256, 0, stream>>>(x, xtb, counts, ovfcnt, N);
    k_scatter_pack<<<(E + 255) / 256, 256, 0, stream>>>(
        edge_dst, edge_src, edge_vec, counts, recb, ovf, ovfcnt, E);
    k_accum<<<(N + 3) / 4, 256, 0, stream>>>(weight, xtb, recb, counts, out, N);
    k_overflow<<<16, 256, 0, stream>>>(weight, xtb, edge_vec, edge_src, edge_dst,
                                       ovf, ovfcnt, out);
}

// Round 7
// 168.924 us; speedup vs baseline: 4.9996x; 1.0757x over previous
//
#include <hip/hip_runtime.h>

#define MUL 64
#define XROW 256   // 4*MUL floats per node row
#define WROW 320   // 5*MUL floats per edge weight row
#define CAP  64    // fixed bucket capacity per node (avg degree 8, Poisson tail << 64)

typedef int   i32x4 __attribute__((ext_vector_type(4)));
typedef float f32x4 __attribute__((ext_vector_type(4)));

struct __align__(32) Rec { int e, src; float rx, ry, rz; int p0, p1, p2; };

// ---------- phase 1: direct bucket placement (counts zeroed by memset) ----------

__global__ void k_scatter_pack(const int* __restrict__ dst, const int* __restrict__ src,
                               const float* __restrict__ ev,
                               int* __restrict__ counts, Rec* __restrict__ rec,
                               int* __restrict__ ovf, int* __restrict__ ovfcnt, int E) {
    int i = blockIdx.x * blockDim.x + threadIdx.x;
    if (i >= E) return;
    const int d = dst[i];
    const int slot = atomicAdd(&counts[d], 1);
    if (slot >= CAP) {                       // structurally ~impossible; correctness net
        int oi = atomicAdd(ovfcnt, 1);
        ovf[oi] = i;
        return;
    }
    const float ex = ev[3 * i + 0], ey = ev[3 * i + 1], ez = ev[3 * i + 2];
    const float rn = 1.0f / fmaxf(sqrtf(ex * ex + ey * ey + ez * ez), 1e-12f);
    Rec r;
    r.e = i; r.src = src[i];
    r.rx = ex * rn; r.ry = ey * rn; r.rz = ez * rn;
    r.p0 = 0; r.p1 = 0; r.p2 = 0;
    rec[(size_t)d * CAP + slot] = r;
}

// ---------- phase 2: one wave per node, 3-stage pipeline, 2-deep w/x prefetch ----------

__global__ __launch_bounds__(256) void k_accum(
    const float* __restrict__ weight,
    const float* __restrict__ x,
    const Rec* __restrict__ rec,
    const int* __restrict__ counts,
    float* __restrict__ out,
    int N)
{
    const int wave = blockIdx.x * (blockDim.x >> 6) + (threadIdx.x >> 6);
    const int lane = threadIdx.x & 63;
    if (wave >= N) return;
    const int n   = wave;
    const int cnt = min(counts[n], CAP);

    const float PW0       = 0.70710678118654752440f; // sqrt(1/2)
    const float INV_SQRT3 = 0.57735026918962576451f; // 1/sqrt(3)
    const float INV_SQRT2 = 0.70710678118654752440f; // sqrt(3)/sqrt(6)

    float a0 = 0.f, a1x = 0.f, a1y = 0.f, a1z = 0.f;

    if (cnt > 0) {
        const size_t base = (size_t)n * CAP;
        const i32x4* ri = (const i32x4*)rec;
        const float* rf = (const float*)rec;
        const int last = cnt - 1;

        // ---- prologue: rec for 0,1,2 ; w/x for 0,1 ----
        i32x4 h0  = ri[2 * (base + 0)];
        float rz0 = rf[8 * (base + 0) + 4];
        const int j1 = (1 < last) ? 1 : last;
        i32x4 h1  = ri[2 * (base + j1)];
        float rz1 = rf[8 * (base + j1) + 4];
        const int j2p = (2 < last) ? 2 : last;
        i32x4 h2  = ri[2 * (base + j2p)];
        float rz2 = rf[8 * (base + j2p) + 4];

        const float* w0p = weight + (size_t)h0.x * WROW;
        float w000 = __builtin_nontemporal_load(w0p + 0 * MUL + lane);
        float w011 = __builtin_nontemporal_load(w0p + 1 * MUL + lane);
        float w101 = __builtin_nontemporal_load(w0p + 2 * MUL + lane);
        float w110 = __builtin_nontemporal_load(w0p + 3 * MUL + lane);
        float w111 = __builtin_nontemporal_load(w0p + 4 * MUL + lane);
        const float* x0p = x + (size_t)h0.y * XROW;
        float xs0 = x0p[lane];
        float x1x = x0p[MUL + 3 * lane + 0];
        float x1y = x0p[MUL + 3 * lane + 1];
        float x1z = x0p[MUL + 3 * lane + 2];

        const float* w1p = weight + (size_t)h1.x * WROW;
        float v000 = __builtin_nontemporal_load(w1p + 0 * MUL + lane);
        float v011 = __builtin_nontemporal_load(w1p + 1 * MUL + lane);
        float v101 = __builtin_nontemporal_load(w1p + 2 * MUL + lane);
        float v110 = __builtin_nontemporal_load(w1p + 3 * MUL + lane);
        float v111 = __builtin_nontemporal_load(w1p + 4 * MUL + lane);
        const float* x1p = x + (size_t)h1.y * XROW;
        float ys0 = x1p[lane];
        float y1x = x1p[MUL + 3 * lane + 0];
        float y1y = x1p[MUL + 3 * lane + 1];
        float y1z = x1p[MUL + 3 * lane + 2];

        for (int i = 0; i < cnt; ++i) {
            // prefetch rec[i+3]
            const int j3 = (i + 3 < last) ? i + 3 : last;
            const i32x4 h3  = ri[2 * (base + j3)];
            const float rz3 = rf[8 * (base + j3) + 4];

            // prefetch w/x for i+2 (rec h2 loaded one iteration ago)
            const float* w2p = weight + (size_t)h2.x * WROW;
            const float u000 = __builtin_nontemporal_load(w2p + 0 * MUL + lane);
            const float u011 = __builtin_nontemporal_load(w2p + 1 * MUL + lane);
            const float u101 = __builtin_nontemporal_load(w2p + 2 * MUL + lane);
            const float u110 = __builtin_nontemporal_load(w2p + 3 * MUL + lane);
            const float u111 = __builtin_nontemporal_load(w2p + 4 * MUL + lane);
            const float* x2p = x + (size_t)h2.y * XROW;
            const float zs0 = x2p[lane];
            const float z1x = x2p[MUL + 3 * lane + 0];
            const float z1y = x2p[MUL + 3 * lane + 1];
            const float z1z = x2p[MUL + 3 * lane + 2];

            // compute iteration i (data loaded two iterations ago)
            const float rx = __int_as_float(h0.z);
            const float ry = __int_as_float(h0.w);
            const float rz = rz0;

            const float dotv = x1x * rx + x1y * ry + x1z * rz;
            a0 += PW0 * (w000 * xs0 + w110 * dotv);

            const float cx = x1y * rz - x1z * ry;
            const float cy = x1z * rx - x1x * rz;
            const float cz = x1x * ry - x1y * rx;

            const float a = w011 * xs0;
            const float b = w101 * INV_SQRT3;
            const float c = w111 * INV_SQRT2;
            a1x += a * rx + b * x1x + c * cx;
            a1y += a * ry + b * x1y + c * cy;
            a1z += a * rz + b * x1z + c * cz;

            // rotate
            h0 = h1; rz0 = rz1;
            h1 = h2; rz1 = rz2;
            h2 = h3; rz2 = rz3;
            w000 = v000; w011 = v011; w101 = v101; w110 = v110; w111 = v111;
            xs0 = ys0; x1x = y1x; x1y = y1y; x1z = y1z;
            v000 = u000; v011 = u011; v101 = u101; v110 = u110; v111 = u111;
            ys0 = zs0; y1x = z1x; y1y = z1y; y1z = z1z;
        }
    }

    float* o = out + (size_t)n * XROW;
    __builtin_nontemporal_store(a0,  o + lane);
    __builtin_nontemporal_store(a1x, o + MUL + 3 * lane + 0);
    __builtin_nontemporal_store(a1y, o + MUL + 3 * lane + 1);
    __builtin_nontemporal_store(a1z, o + MUL + 3 * lane + 2);
}

// ---------- phase 3: drain overflow list (normally empty) ----------

__global__ void k_overflow(const float* __restrict__ weight, const float* __restrict__ x,
                           const float* __restrict__ ev, const int* __restrict__ src,
                           const int* __restrict__ dst,
                           const int* __restrict__ ovf, const int* __restrict__ ovfcnt,
                           float* __restrict__ out) {
    const int nov = *ovfcnt;
    const int wid  = blockIdx.x * (blockDim.x >> 6) + (threadIdx.x >> 6);
    const int lane = threadIdx.x & 63;
    const int nw   = gridDim.x * (blockDim.x >> 6);
    const float PW0 = 0.70710678118654752440f, INV_SQRT3 = 0.57735026918962576451f,
                INV_SQRT2 = 0.70710678118654752440f;
    for (int k = wid; k < nov; k += nw) {
        const int e = ovf[k];
        const int s = src[e], d = dst[e];
        const float ex = ev[3 * e + 0], ey = ev[3 * e + 1], ez = ev[3 * e + 2];
        const float rn = 1.0f / fmaxf(sqrtf(ex * ex + ey * ey + ez * ez), 1e-12f);
        const float rx = ex * rn, ry = ey * rn, rz = ez * rn;
        const float* xr = x + (size_t)s * XROW;
        const float xs0 = xr[lane];
        const float x1x = xr[MUL + 3 * lane + 0], x1y = xr[MUL + 3 * lane + 1],
                    x1z = xr[MUL + 3 * lane + 2];
        const float* w = weight + (size_t)e * WROW;
        const float w000 = w[lane], w011 = w[MUL + lane], w101 = w[2 * MUL + lane],
                    w110 = w[3 * MUL + lane], w111 = w[4 * MUL + lane];
        const float dotv = x1x * rx + x1y * ry + x1z * rz;
        const float m0 = PW0 * (w000 * xs0 + w110 * dotv);
        const float cx = x1y * rz - x1z * ry;
        const float cy = x1z * rx - x1x * rz;
        const float cz = x1x * ry - x1y * rx;
        const float a = w011 * xs0, b = w101 * INV_SQRT3, c = w111 * INV_SQRT2;
        float* o = out + (size_t)d * XROW;
        atomicAdd(o + lane, m0);
        atomicAdd(o + MUL + 3 * lane + 0, a * rx + b * x1x + c * cx);
        atomicAdd(o + MUL + 3 * lane + 1, a * ry + b * x1y + c * cy);
        atomicAdd(o + MUL + 3 * lane + 2, a * rz + b * x1z + c * cz);
    }
}

// ---------- fallback (ws too small): atomic edge-parallel version ----------

__global__ __launch_bounds__(256) void tpconv_edge_kernel(
    const float* __restrict__ x, const float* __restrict__ edge_vec,
    const float* __restrict__ weight, const int* __restrict__ edge_src,
    const int* __restrict__ edge_dst, float* __restrict__ out, int E)
{
    const int wave = blockIdx.x * (blockDim.x >> 6) + (threadIdx.x >> 6);
    const int lane = threadIdx.x & 63;
    if (wave >= E) return;
    const int e = wave;
    const int src = edge_src[e];
    const int dst = edge_dst[e];
    const float evx = edge_vec[3 * e + 0], evy = edge_vec[3 * e + 1], evz = edge_vec[3 * e + 2];
    const float rn = 1.0f / fmaxf(sqrtf(evx * evx + evy * evy + evz * evz), 1e-12f);
    const float rx = evx * rn, ry = evy * rn, rz = evz * rn;
    const float* xr = x + (size_t)src * XROW;
    const float xs0 = xr[lane];
    const float x1x = xr[MUL + 3 * lane + 0], x1y = xr[MUL + 3 * lane + 1], x1z = xr[MUL + 3 * lane + 2];
    const float* w = weight + (size_t)e * WROW;
    const float w000 = w[lane], w011 = w[MUL + lane], w101 = w[2 * MUL + lane],
                w110 = w[3 * MUL + lane], w111 = w[4 * MUL + lane];
    const float PW0 = 0.70710678118654752440f, INV_SQRT3 = 0.57735026918962576451f,
                INV_SQRT2 = 0.70710678118654752440f;
    const float dotv = x1x * rx + x1y * ry + x1z * rz;
    const float m0 = PW0 * (w000 * xs0 + w110 * dotv);
    const float cx = x1y * rz - x1z * ry, cy = x1z * rx - x1x * rz, cz = x1x * ry - x1y * rx;
    const float a = w011 * xs0, b = w101 * INV_SQRT3, c = w111 * INV_SQRT2;
    float* o = out + (size_t)dst * XROW;
    atomicAdd(o + lane, m0);
    atomicAdd(o + MUL + 3 * lane + 0, a * rx + b * x1x + c * cx);
    atomicAdd(o + MUL + 3 * lane + 1, a * ry + b * x1y + c * cy);
    atomicAdd(o + MUL + 3 * lane + 2, a * rz + b * x1z + c * cz);
}

extern "C" void kernel_launch(void* const* d_in, const int* in_sizes, int n_in,
                              void* d_out, int out_size, void* d_ws, size_t ws_size,
                              hipStream_t stream) {
    const float* x        = (const float*)d_in[0];
    const float* edge_vec = (const float*)d_in[1];
    const float* weight   = (const float*)d_in[2];
    const int*   edge_src = (const int*)d_in[3];
    const int*   edge_dst = (const int*)d_in[4];
    float* out = (float*)d_out;

    const int E = in_sizes[3];
    const int N = in_sizes[0] / XROW;      // 50000

    // workspace layout
    int*  counts = (int*)d_ws;                                   // N ints
    int*  ovfcnt = counts + N;                                   // 1 int (pad 8)
    int*  ovf    = ovfcnt + 8;                                   // E ints
    char* p      = (char*)(ovf + E);
    p += (64 - ((size_t)p & 63)) & 63;                           // align 64
    Rec*  recb   = (Rec*)p;                                      // N*CAP*32 B
    const size_t need = ((char*)recb + (size_t)N * CAP * sizeof(Rec)) - (char*)d_ws;

    if (ws_size < need) {
        (void)hipMemsetAsync(d_out, 0, (size_t)out_size * sizeof(float), stream);
        tpconv_edge_kernel<<<(E + 3) / 4, 256, 0, stream>>>(
            x, edge_vec, weight, edge_src, edge_dst, out, E);
        return;
    }

    // zero counts + ovfcnt in one small async memset (graph-capture safe)
    (void)hipMemsetAsync(counts, 0, (size_t)(N + 8) * sizeof(int), stream);

    k_scatter_pack<<<(E + 255) / 256, 256, 0, stream>>>(
        edge_dst, edge_src, edge_vec, counts, recb, ovf, ovfcnt, E);
    k_accum<<<(N + 3) / 4, 256, 0, stream>>>(weight, x, recb, counts, out, N);
    k_overflow<<<16, 256, 0, stream>>>(weight, x, edge_vec, edge_src, edge_dst,
                                       ovf, ovfcnt, out);
}

// Round 8
// 167.409 us; speedup vs baseline: 5.0448x; 1.0090x over previous
//
#include <hip/hip_runtime.h>

#define MUL 64
#define XROW 256   // 4*MUL floats per node row
#define WROW 320   // 5*MUL floats per edge weight row
#define CAP  64    // fixed bucket capacity per node (avg degree 8, Poisson tail << 64)

typedef int   i32x4 __attribute__((ext_vector_type(4)));
typedef float f32x4 __attribute__((ext_vector_type(4)));

// 16-B record: { e | sign(rz)<<31, src, bits(rx), bits(ry) }; rz reconstructed.

// ---------- phase 1: direct bucket placement (counts zeroed by memset) ----------

__global__ void k_scatter_pack(const int* __restrict__ dst, const int* __restrict__ src,
                               const float* __restrict__ ev,
                               int* __restrict__ counts, i32x4* __restrict__ rec,
                               int* __restrict__ ovf, int* __restrict__ ovfcnt, int E) {
    int i = blockIdx.x * blockDim.x + threadIdx.x;
    if (i >= E) return;
    const int d = dst[i];
    const int slot = atomicAdd(&counts[d], 1);
    if (slot >= CAP) {                       // structurally ~impossible; correctness net
        int oi = atomicAdd(ovfcnt, 1);
        ovf[oi] = i;
        return;
    }
    const float ex = ev[3 * i + 0], ey = ev[3 * i + 1], ez = ev[3 * i + 2];
    const float rn = 1.0f / fmaxf(sqrtf(ex * ex + ey * ey + ez * ez), 1e-12f);
    const float rx = ex * rn, ry = ey * rn, rz = ez * rn;
    i32x4 r;
    r.x = (int)((unsigned)i | (rz < 0.0f ? 0x80000000u : 0u));
    r.y = src[i];
    r.z = __float_as_int(rx);
    r.w = __float_as_int(ry);
    rec[(size_t)d * CAP + slot] = r;
}

// ---------- phase 2: one wave per node, 3-stage pipeline, 2-deep w/x prefetch ----------

__global__ __launch_bounds__(256) void k_accum(
    const float* __restrict__ weight,
    const float* __restrict__ x,
    const i32x4* __restrict__ rec,
    const int* __restrict__ counts,
    float* __restrict__ out,
    int N)
{
    const int wave = blockIdx.x * (blockDim.x >> 6) + (threadIdx.x >> 6);
    const int lane = threadIdx.x & 63;
    if (wave >= N) return;
    const int n   = wave;
    const int cnt = min(counts[n], CAP);

    const float PW0       = 0.70710678118654752440f; // sqrt(1/2)
    const float INV_SQRT3 = 0.57735026918962576451f; // 1/sqrt(3)
    const float INV_SQRT2 = 0.70710678118654752440f; // sqrt(3)/sqrt(6)

    float a0 = 0.f, a1x = 0.f, a1y = 0.f, a1z = 0.f;

    if (cnt > 0) {
        const size_t base = (size_t)n * CAP;
        const int last = cnt - 1;

        // ---- prologue: rec for 0,1,2 ; w/x for 0,1 ----
        i32x4 h0 = rec[base + 0];
        const int j1 = (1 < last) ? 1 : last;
        i32x4 h1 = rec[base + j1];
        const int j2p = (2 < last) ? 2 : last;
        i32x4 h2 = rec[base + j2p];

        const float* w0p = weight + (size_t)(h0.x & 0x7FFFFFFF) * WROW;
        float w000 = __builtin_nontemporal_load(w0p + 0 * MUL + lane);
        float w011 = __builtin_nontemporal_load(w0p + 1 * MUL + lane);
        float w101 = __builtin_nontemporal_load(w0p + 2 * MUL + lane);
        float w110 = __builtin_nontemporal_load(w0p + 3 * MUL + lane);
        float w111 = __builtin_nontemporal_load(w0p + 4 * MUL + lane);
        const float* x0p = x + (size_t)h0.y * XROW;
        float xs0 = x0p[lane];
        float x1x = x0p[MUL + 3 * lane + 0];
        float x1y = x0p[MUL + 3 * lane + 1];
        float x1z = x0p[MUL + 3 * lane + 2];

        const float* w1p = weight + (size_t)(h1.x & 0x7FFFFFFF) * WROW;
        float v000 = __builtin_nontemporal_load(w1p + 0 * MUL + lane);
        float v011 = __builtin_nontemporal_load(w1p + 1 * MUL + lane);
        float v101 = __builtin_nontemporal_load(w1p + 2 * MUL + lane);
        float v110 = __builtin_nontemporal_load(w1p + 3 * MUL + lane);
        float v111 = __builtin_nontemporal_load(w1p + 4 * MUL + lane);
        const float* x1p = x + (size_t)h1.y * XROW;
        float ys0 = x1p[lane];
        float y1x = x1p[MUL + 3 * lane + 0];
        float y1y = x1p[MUL + 3 * lane + 1];
        float y1z = x1p[MUL + 3 * lane + 2];

        for (int i = 0; i < cnt; ++i) {
            // prefetch rec[i+3]
            const int j3 = (i + 3 < last) ? i + 3 : last;
            const i32x4 h3 = rec[base + j3];

            // prefetch w/x for i+2 (rec h2 loaded one iteration ago)
            const float* w2p = weight + (size_t)(h2.x & 0x7FFFFFFF) * WROW;
            const float u000 = __builtin_nontemporal_load(w2p + 0 * MUL + lane);
            const float u011 = __builtin_nontemporal_load(w2p + 1 * MUL + lane);
            const float u101 = __builtin_nontemporal_load(w2p + 2 * MUL + lane);
            const float u110 = __builtin_nontemporal_load(w2p + 3 * MUL + lane);
            const float u111 = __builtin_nontemporal_load(w2p + 4 * MUL + lane);
            const float* x2p = x + (size_t)h2.y * XROW;
            const float zs0 = x2p[lane];
            const float z1x = x2p[MUL + 3 * lane + 0];
            const float z1y = x2p[MUL + 3 * lane + 1];
            const float z1z = x2p[MUL + 3 * lane + 2];

            // compute iteration i (data loaded two iterations ago)
            const float rx = __int_as_float(h0.z);
            const float ry = __int_as_float(h0.w);
            float rz = sqrtf(fmaxf(0.0f, 1.0f - rx * rx - ry * ry));
            rz = (h0.x < 0) ? -rz : rz;

            const float dotv = x1x * rx + x1y * ry + x1z * rz;
            a0 += PW0 * (w000 * xs0 + w110 * dotv);

            const float cx = x1y * rz - x1z * ry;
            const float cy = x1z * rx - x1x * rz;
            const float cz = x1x * ry - x1y * rx;

            const float a = w011 * xs0;
            const float b = w101 * INV_SQRT3;
            const float c = w111 * INV_SQRT2;
            a1x += a * rx + b * x1x + c * cx;
            a1y += a * ry + b * x1y + c * cy;
            a1z += a * rz + b * x1z + c * cz;

            // rotate
            h0 = h1; h1 = h2; h2 = h3;
            w000 = v000; w011 = v011; w101 = v101; w110 = v110; w111 = v111;
            xs0 = ys0; x1x = y1x; x1y = y1y; x1z = y1z;
            v000 = u000; v011 = u011; v101 = u101; v110 = u110; v111 = u111;
            ys0 = zs0; y1x = z1x; y1y = z1y; y1z = z1z;
        }
    }

    float* o = out + (size_t)n * XROW;
    __builtin_nontemporal_store(a0,  o + lane);
    __builtin_nontemporal_store(a1x, o + MUL + 3 * lane + 0);
    __builtin_nontemporal_store(a1y, o + MUL + 3 * lane + 1);
    __builtin_nontemporal_store(a1z, o + MUL + 3 * lane + 2);
}

// ---------- phase 3: drain overflow list (normally empty) ----------

__global__ void k_overflow(const float* __restrict__ weight, const float* __restrict__ x,
                           const float* __restrict__ ev, const int* __restrict__ src,
                           const int* __restrict__ dst,
                           const int* __restrict__ ovf, const int* __restrict__ ovfcnt,
                           float* __restrict__ out) {
    const int nov = *ovfcnt;
    const int wid  = blockIdx.x * (blockDim.x >> 6) + (threadIdx.x >> 6);
    const int lane = threadIdx.x & 63;
    const int nw   = gridDim.x * (blockDim.x >> 6);
    const float PW0 = 0.70710678118654752440f, INV_SQRT3 = 0.57735026918962576451f,
                INV_SQRT2 = 0.70710678118654752440f;
    for (int k = wid; k < nov; k += nw) {
        const int e = ovf[k];
        const int s = src[e], d = dst[e];
        const float ex = ev[3 * e + 0], ey = ev[3 * e + 1], ez = ev[3 * e + 2];
        const float rn = 1.0f / fmaxf(sqrtf(ex * ex + ey * ey + ez * ez), 1e-12f);
        const float rx = ex * rn, ry = ey * rn, rz = ez * rn;
        const float* xr = x + (size_t)s * XROW;
        const float xs0 = xr[lane];
        const float x1x = xr[MUL + 3 * lane + 0], x1y = xr[MUL + 3 * lane + 1],
                    x1z = xr[MUL + 3 * lane + 2];
        const float* w = weight + (size_t)e * WROW;
        const float w000 = w[lane], w011 = w[MUL + lane], w101 = w[2 * MUL + lane],
                    w110 = w[3 * MUL + lane], w111 = w[4 * MUL + lane];
        const float dotv = x1x * rx + x1y * ry + x1z * rz;
        const float m0 = PW0 * (w000 * xs0 + w110 * dotv);
        const float cx = x1y * rz - x1z * ry;
        const float cy = x1z * rx - x1x * rz;
        const float cz = x1x * ry - x1y * rx;
        const float a = w011 * xs0, b = w101 * INV_SQRT3, c = w111 * INV_SQRT2;
        float* o = out + (size_t)d * XROW;
        atomicAdd(o + lane, m0);
        atomicAdd(o + MUL + 3 * lane + 0, a * rx + b * x1x + c * cx);
        atomicAdd(o + MUL + 3 * lane + 1, a * ry + b * x1y + c * cy);
        atomicAdd(o + MUL + 3 * lane + 2, a * rz + b * x1z + c * cz);
    }
}

// ---------- fallback (ws too small): atomic edge-parallel version ----------

__global__ __launch_bounds__(256) void tpconv_edge_kernel(
    const float* __restrict__ x, const float* __restrict__ edge_vec,
    const float* __restrict__ weight, const int* __restrict__ edge_src,
    const int* __restrict__ edge_dst, float* __restrict__ out, int E)
{
    const int wave = blockIdx.x * (blockDim.x >> 6) + (threadIdx.x >> 6);
    const int lane = threadIdx.x & 63;
    if (wave >= E) return;
    const int e = wave;
    const int src = edge_src[e];
    const int dst = edge_dst[e];
    const float evx = edge_vec[3 * e + 0], evy = edge_vec[3 * e + 1], evz = edge_vec[3 * e + 2];
    const float rn = 1.0f / fmaxf(sqrtf(evx * evx + evy * evy + evz * evz), 1e-12f);
    const float rx = evx * rn, ry = evy * rn, rz = evz * rn;
    const float* xr = x + (size_t)src * XROW;
    const float xs0 = xr[lane];
    const float x1x = xr[MUL + 3 * lane + 0], x1y = xr[MUL + 3 * lane + 1], x1z = xr[MUL + 3 * lane + 2];
    const float* w = weight + (size_t)e * WROW;
    const float w000 = w[lane], w011 = w[MUL + lane], w101 = w[2 * MUL + lane],
                w110 = w[3 * MUL + lane], w111 = w[4 * MUL + lane];
    const float PW0 = 0.70710678118654752440f, INV_SQRT3 = 0.57735026918962576451f,
                INV_SQRT2 = 0.70710678118654752440f;
    const float dotv = x1x * rx + x1y * ry + x1z * rz;
    const float m0 = PW0 * (w000 * xs0 + w110 * dotv);
    const float cx = x1y * rz - x1z * ry, cy = x1z * rx - x1x * rz, cz = x1x * ry - x1y * rx;
    const float a = w011 * xs0, b = w101 * INV_SQRT3, c = w111 * INV_SQRT2;
    float* o = out + (size_t)dst * XROW;
    atomicAdd(o + lane, m0);
    atomicAdd(o + MUL + 3 * lane + 0, a * rx + b * x1x + c * cx);
    atomicAdd(o + MUL + 3 * lane + 1, a * ry + b * x1y + c * cy);
    atomicAdd(o + MUL + 3 * lane + 2, a * rz + b * x1z + c * cz);
}

extern "C" void kernel_launch(void* const* d_in, const int* in_sizes, int n_in,
                              void* d_out, int out_size, void* d_ws, size_t ws_size,
                              hipStream_t stream) {
    const float* x        = (const float*)d_in[0];
    const float* edge_vec = (const float*)d_in[1];
    const float* weight   = (const float*)d_in[2];
    const int*   edge_src = (const int*)d_in[3];
    const int*   edge_dst = (const int*)d_in[4];
    float* out = (float*)d_out;

    const int E = in_sizes[3];
    const int N = in_sizes[0] / XROW;      // 50000

    // workspace layout
    int*  counts = (int*)d_ws;                                   // N ints
    int*  ovfcnt = counts + N;                                   // 1 int (pad 8)
    int*  ovf    = ovfcnt + 8;                                   // E ints
    char* p      = (char*)(ovf + E);
    p += (64 - ((size_t)p & 63)) & 63;                           // align 64
    i32x4* recb  = (i32x4*)p;                                    // N*CAP*16 B
    const size_t need = ((char*)recb + (size_t)N * CAP * sizeof(i32x4)) - (char*)d_ws;

    if (ws_size < need) {
        (void)hipMemsetAsync(d_out, 0, (size_t)out_size * sizeof(float), stream);
        tpconv_edge_kernel<<<(E + 3) / 4, 256, 0, stream>>>(
            x, edge_vec, weight, edge_src, edge_dst, out, E);
        return;
    }

    // zero counts + ovfcnt in one small async memset (graph-capture safe)
    (void)hipMemsetAsync(counts, 0, (size_t)(N + 8) * sizeof(int), stream);

    k_scatter_pack<<<(E + 255) / 256, 256, 0, stream>>>(
        edge_dst, edge_src, edge_vec, counts, recb, ovf, ovfcnt, E);
    k_accum<<<(N + 3) / 4, 256, 0, stream>>>(weight, x, recb, counts, out, N);
    k_overflow<<<16, 256, 0, stream>>>(weight, x, edge_vec, edge_src, edge_dst,
                                       ovf, ovfcnt, out);
}

// Round 9
// 166.410 us; speedup vs baseline: 5.0751x; 1.0060x over previous
//
#include <hip/hip_runtime.h>

#define MUL 64
#define XROW 256   // 4*MUL floats per node row
#define WROW 320   // 5*MUL floats per edge weight row
#define CAP  64    // fixed bucket capacity per node (avg degree 8, Poisson tail << 64)

typedef int   i32x4 __attribute__((ext_vector_type(4)));

// 16-B record: { e | sign(rz)<<31, src, bits(rx), bits(ry) }; rz reconstructed.

// ---------- phase 1: direct bucket placement (counts zeroed by memset) ----------

__global__ void k_scatter_pack(const int* __restrict__ dst, const int* __restrict__ src,
                               const float* __restrict__ ev,
                               int* __restrict__ counts, i32x4* __restrict__ rec,
                               int* __restrict__ ovf, int* __restrict__ ovfcnt, int E) {
    int i = blockIdx.x * blockDim.x + threadIdx.x;
    if (i >= E) return;
    const int d = dst[i];
    const int slot = atomicAdd(&counts[d], 1);
    if ((unsigned)slot >= (unsigned)CAP) {   // also guards stale/poisoned counts (slot<0)
        int oi = atomicAdd(ovfcnt, 1);
        if ((unsigned)oi < (unsigned)E) ovf[oi] = i;   // drop only in pathological replays
        return;
    }
    const float ex = ev[3 * i + 0], ey = ev[3 * i + 1], ez = ev[3 * i + 2];
    const float rn = 1.0f / fmaxf(sqrtf(ex * ex + ey * ey + ez * ez), 1e-12f);
    const float rx = ex * rn, ry = ey * rn, rz = ez * rn;
    i32x4 r;
    r.x = (int)((unsigned)i | (rz < 0.0f ? 0x80000000u : 0u));
    r.y = src[i];
    r.z = __float_as_int(rx);
    r.w = __float_as_int(ry);
    rec[(size_t)d * CAP + slot] = r;
}

// ---------- phase 2: one wave per node, 3-stage pipeline, 2-deep w/x prefetch ----------
// Overflow entries (normally zero) are drained inline by the owning wave before its
// final store, so no separate kernel and no store/atomic ordering hazard.

__global__ __launch_bounds__(256) void k_accum(
    const float* __restrict__ weight,
    const float* __restrict__ x,
    const float* __restrict__ ev,
    const int* __restrict__ edge_src,
    const int* __restrict__ edge_dst,
    const i32x4* __restrict__ rec,
    const int* __restrict__ counts,
    const int* __restrict__ ovf,
    const int* __restrict__ ovfcnt,
    float* __restrict__ out,
    int N, int E)
{
    const int wave = blockIdx.x * (blockDim.x >> 6) + (threadIdx.x >> 6);
    const int lane = threadIdx.x & 63;
    if (wave >= N) return;
    const int n = wave;
    int cnt = counts[n];
    cnt = (cnt < 0) ? 0 : ((cnt > CAP) ? CAP : cnt);

    const float PW0       = 0.70710678118654752440f; // sqrt(1/2)
    const float INV_SQRT3 = 0.57735026918962576451f; // 1/sqrt(3)
    const float INV_SQRT2 = 0.70710678118654752440f; // sqrt(3)/sqrt(6)

    float a0 = 0.f, a1x = 0.f, a1y = 0.f, a1z = 0.f;

    if (cnt > 0) {
        const size_t base = (size_t)n * CAP;
        const int last = cnt - 1;

        // ---- prologue: rec for 0,1,2 ; w/x for 0,1 ----
        i32x4 h0 = rec[base + 0];
        const int j1 = (1 < last) ? 1 : last;
        i32x4 h1 = rec[base + j1];
        const int j2p = (2 < last) ? 2 : last;
        i32x4 h2 = rec[base + j2p];

        const float* w0p = weight + (size_t)(h0.x & 0x7FFFFFFF) * WROW;
        float w000 = __builtin_nontemporal_load(w0p + 0 * MUL + lane);
        float w011 = __builtin_nontemporal_load(w0p + 1 * MUL + lane);
        float w101 = __builtin_nontemporal_load(w0p + 2 * MUL + lane);
        float w110 = __builtin_nontemporal_load(w0p + 3 * MUL + lane);
        float w111 = __builtin_nontemporal_load(w0p + 4 * MUL + lane);
        const float* x0p = x + (size_t)h0.y * XROW;
        float xs0 = x0p[lane];
        float x1x = x0p[MUL + 3 * lane + 0];
        float x1y = x0p[MUL + 3 * lane + 1];
        float x1z = x0p[MUL + 3 * lane + 2];

        const float* w1p = weight + (size_t)(h1.x & 0x7FFFFFFF) * WROW;
        float v000 = __builtin_nontemporal_load(w1p + 0 * MUL + lane);
        float v011 = __builtin_nontemporal_load(w1p + 1 * MUL + lane);
        float v101 = __builtin_nontemporal_load(w1p + 2 * MUL + lane);
        float v110 = __builtin_nontemporal_load(w1p + 3 * MUL + lane);
        float v111 = __builtin_nontemporal_load(w1p + 4 * MUL + lane);
        const float* x1p = x + (size_t)h1.y * XROW;
        float ys0 = x1p[lane];
        float y1x = x1p[MUL + 3 * lane + 0];
        float y1y = x1p[MUL + 3 * lane + 1];
        float y1z = x1p[MUL + 3 * lane + 2];

        for (int i = 0; i < cnt; ++i) {
            // prefetch rec[i+3]
            const int j3 = (i + 3 < last) ? i + 3 : last;
            const i32x4 h3 = rec[base + j3];

            // prefetch w/x for i+2 (rec h2 loaded one iteration ago)
            const float* w2p = weight + (size_t)(h2.x & 0x7FFFFFFF) * WROW;
            const float u000 = __builtin_nontemporal_load(w2p + 0 * MUL + lane);
            const float u011 = __builtin_nontemporal_load(w2p + 1 * MUL + lane);
            const float u101 = __builtin_nontemporal_load(w2p + 2 * MUL + lane);
            const float u110 = __builtin_nontemporal_load(w2p + 3 * MUL + lane);
            const float u111 = __builtin_nontemporal_load(w2p + 4 * MUL + lane);
            const float* x2p = x + (size_t)h2.y * XROW;
            const float zs0 = x2p[lane];
            const float z1x = x2p[MUL + 3 * lane + 0];
            const float z1y = x2p[MUL + 3 * lane + 1];
            const float z1z = x2p[MUL + 3 * lane + 2];

            // compute iteration i (data loaded two iterations ago)
            const float rx = __int_as_float(h0.z);
            const float ry = __int_as_float(h0.w);
            float rz = sqrtf(fmaxf(0.0f, 1.0f - rx * rx - ry * ry));
            rz = (h0.x < 0) ? -rz : rz;

            const float dotv = x1x * rx + x1y * ry + x1z * rz;
            a0 += PW0 * (w000 * xs0 + w110 * dotv);

            const float cx = x1y * rz - x1z * ry;
            const float cy = x1z * rx - x1x * rz;
            const float cz = x1x * ry - x1y * rx;

            const float a = w011 * xs0;
            const float b = w101 * INV_SQRT3;
            const float c = w111 * INV_SQRT2;
            a1x += a * rx + b * x1x + c * cx;
            a1y += a * ry + b * x1y + c * cy;
            a1z += a * rz + b * x1z + c * cz;

            // rotate
            h0 = h1; h1 = h2; h2 = h3;
            w000 = v000; w011 = v011; w101 = v101; w110 = v110; w111 = v111;
            xs0 = ys0; x1x = y1x; x1y = y1y; x1z = y1z;
            v000 = u000; v011 = u011; v101 = u101; v110 = u110; v111 = u111;
            ys0 = zs0; y1x = z1x; y1y = z1y; y1z = z1z;
        }
    }

    // ---- inline overflow drain (normally nov == 0) ----
    int nov = *ovfcnt;
    if (nov < 0 || nov > E) nov = 0;
    for (int k = 0; k < nov; ++k) {
        const int e = ovf[k];
        if (edge_dst[e] != n) continue;          // wave-uniform
        const int s = edge_src[e];
        const float ex = ev[3 * e + 0], ey = ev[3 * e + 1], ez = ev[3 * e + 2];
        const float rn = 1.0f / fmaxf(sqrtf(ex * ex + ey * ey + ez * ez), 1e-12f);
        const float rx = ex * rn, ry = ey * rn, rz = ez * rn;
        const float* xr = x + (size_t)s * XROW;
        const float xs0 = xr[lane];
        const float x1x = xr[MUL + 3 * lane + 0], x1y = xr[MUL + 3 * lane + 1],
                    x1z = xr[MUL + 3 * lane + 2];
        const float* w = weight + (size_t)e * WROW;
        const float w000 = w[lane], w011 = w[MUL + lane], w101 = w[2 * MUL + lane],
                    w110 = w[3 * MUL + lane], w111 = w[4 * MUL + lane];
        const float dotv = x1x * rx + x1y * ry + x1z * rz;
        a0 += PW0 * (w000 * xs0 + w110 * dotv);
        const float cx = x1y * rz - x1z * ry;
        const float cy = x1z * rx - x1x * rz;
        const float cz = x1x * ry - x1y * rx;
        const float a = w011 * xs0, b = w101 * INV_SQRT3, c = w111 * INV_SQRT2;
        a1x += a * rx + b * x1x + c * cx;
        a1y += a * ry + b * x1y + c * cy;
        a1z += a * rz + b * x1z + c * cz;
    }

    float* o = out + (size_t)n * XROW;
    __builtin_nontemporal_store(a0,  o + lane);
    __builtin_nontemporal_store(a1x, o + MUL + 3 * lane + 0);
    __builtin_nontemporal_store(a1y, o + MUL + 3 * lane + 1);
    __builtin_nontemporal_store(a1z, o + MUL + 3 * lane + 2);
}

// ---------- fallback (ws too small): atomic edge-parallel version ----------

__global__ __launch_bounds__(256) void tpconv_edge_kernel(
    const float* __restrict__ x, const float* __restrict__ edge_vec,
    const float* __restrict__ weight, const int* __restrict__ edge_src,
    const int* __restrict__ edge_dst, float* __restrict__ out, int E)
{
    const int wave = blockIdx.x * (blockDim.x >> 6) + (threadIdx.x >> 6);
    const int lane = threadIdx.x & 63;
    if (wave >= E) return;
    const int e = wave;
    const int src = edge_src[e];
    const int dst = edge_dst[e];
    const float evx = edge_vec[3 * e + 0], evy = edge_vec[3 * e + 1], evz = edge_vec[3 * e + 2];
    const float rn = 1.0f / fmaxf(sqrtf(evx * evx + evy * evy + evz * evz), 1e-12f);
    const float rx = evx * rn, ry = evy * rn, rz = evz * rn;
    const float* xr = x + (size_t)src * XROW;
    const float xs0 = xr[lane];
    const float x1x = xr[MUL + 3 * lane + 0], x1y = xr[MUL + 3 * lane + 1], x1z = xr[MUL + 3 * lane + 2];
    const float* w = weight + (size_t)e * WROW;
    const float w000 = w[lane], w011 = w[MUL + lane], w101 = w[2 * MUL + lane],
                w110 = w[3 * MUL + lane], w111 = w[4 * MUL + lane];
    const float PW0 = 0.70710678118654752440f, INV_SQRT3 = 0.57735026918962576451f,
                INV_SQRT2 = 0.70710678118654752440f;
    const float dotv = x1x * rx + x1y * ry + x1z * rz;
    const float m0 = PW0 * (w000 * xs0 + w110 * dotv);
    const float cx = x1y * rz - x1z * ry, cy = x1z * rx - x1x * rz, cz = x1x * ry - x1y * rx;
    const float a = w011 * xs0, b = w101 * INV_SQRT3, c = w111 * INV_SQRT2;
    float* o = out + (size_t)dst * XROW;
    atomicAdd(o + lane, m0);
    atomicAdd(o + MUL + 3 * lane + 0, a * rx + b * x1x + c * cx);
    atomicAdd(o + MUL + 3 * lane + 1, a * ry + b * x1y + c * cy);
    atomicAdd(o + MUL + 3 * lane + 2, a * rz + b * x1z + c * cz);
}

extern "C" void kernel_launch(void* const* d_in, const int* in_sizes, int n_in,
                              void* d_out, int out_size, void* d_ws, size_t ws_size,
                              hipStream_t stream) {
    const float* x        = (const float*)d_in[0];
    const float* edge_vec = (const float*)d_in[1];
    const float* weight   = (const float*)d_in[2];
    const int*   edge_src = (const int*)d_in[3];
    const int*   edge_dst = (const int*)d_in[4];
    float* out = (float*)d_out;

    const int E = in_sizes[3];
    const int N = in_sizes[0] / XROW;      // 50000

    // workspace layout
    int*  counts = (int*)d_ws;                                   // N ints
    int*  ovfcnt = counts + N;                                   // 1 int (pad 8)
    int*  ovf    = ovfcnt + 8;                                   // E ints
    char* p      = (char*)(ovf + E);
    p += (64 - ((size_t)p & 63)) & 63;                           // align 64
    i32x4* recb  = (i32x4*)p;                                    // N*CAP*16 B
    const size_t need = ((char*)recb + (size_t)N * CAP * sizeof(i32x4)) - (char*)d_ws;

    if (ws_size < need) {
        (void)hipMemsetAsync(d_out, 0, (size_t)out_size * sizeof(float), stream);
        tpconv_edge_kernel<<<(E + 3) / 4, 256, 0, stream>>>(
            x, edge_vec, weight, edge_src, edge_dst, out, E);
        return;
    }

    // zero counts + ovfcnt in one small async memset (graph-capture safe)
    (void)hipMemsetAsync(counts, 0, (size_t)(N + 8) * sizeof(int), stream);

    k_scatter_pack<<<(E + 255) / 256, 256, 0, stream>>>(
        edge_dst, edge_src, edge_vec, counts, recb, ovf, ovfcnt, E);
    k_accum<<<(N + 3) / 4, 256, 0, stream>>>(
        weight, x, edge_vec, edge_src, edge_dst, recb, counts, ovf, ovfcnt, out, N, E);
}